// Round 6
// baseline (561.489 us; speedup 1.0000x reference)
//
#include <hip/hip_runtime.h>
#include <hip/hip_bf16.h>

// Problem constants: B=64, S=512, H=768, L=9
#define NB 64
#define NS 512
#define NH 768
#define NL 9
#define NROWS (NB*NS)          // 32768
#define EMN (NROWS*NL)         // 294912
#define NGEMM 8192             // gemm blocks in fused grid

// per-batch strides
#define VST  4617              // floats per batch for v-history
#define BPST 4616              // bytes  per batch for s_bp

__device__ __forceinline__ float readlane_f(float v, int l) {
    return __int_as_float(__builtin_amdgcn_readlane(__float_as_int(v), l));
}
__device__ __forceinline__ unsigned long long readlane_u64(unsigned long long v, int l) {
    unsigned int lo = (unsigned int)__builtin_amdgcn_readlane((int)(unsigned int)(v & 0xffffffffULL), l);
    unsigned int hi = (unsigned int)__builtin_amdgcn_readlane((int)(unsigned int)(v >> 32), l);
    return ((unsigned long long)hi << 32) | (unsigned long long)lo;
}
template <int CTRL>
__device__ __forceinline__ float dpp_add(float x) {
    int t = __builtin_amdgcn_update_dpp(0, __float_as_int(x), CTRL, 0xf, 0xf, false);
    return x + __int_as_float(t);
}
__device__ __forceinline__ float wave_sum_to63(float x) {
    x = dpp_add<0x111>(x);  // row_shr:1
    x = dpp_add<0x112>(x);  // row_shr:2
    x = dpp_add<0x114>(x);  // row_shr:4
    x = dpp_add<0x118>(x);  // row_shr:8
    x = dpp_add<0x142>(x);  // row_bcast:15
    x = dpp_add<0x143>(x);  // row_bcast:31 -> lane63 = wave sum
    return x;
}
// ds_swizzle row-broadcast: lane receives value of lane I of its 16-lane row.
template <int I>
__device__ __forceinline__ float rowbc(float x) {
    return __int_as_float(__builtin_amdgcn_ds_swizzle(__float_as_int(x), (I << 5) | 0x10));
}
// Bounded device-coherent poll: wait until *fp >= 8 (chunk complete).
__device__ __forceinline__ void poll8(unsigned int* fp) {
    int guard = 0;
    while (atomicAdd(fp, 0u) < 8u) {
        __builtin_amdgcn_s_sleep(32);
        if (++guard > (1 << 20)) break;   // safety valve: fail absmax, never hang
    }
}

// =====================================================================
// FUSED kernel: blocks [0,NGEMM) = emissions GEMM (t-major, flag release)
//               blocks [NGEMM, NGEMM+32) = DP (chunk-gated chains)
// =====================================================================
__global__ __launch_bounds__(256) void k_fused(const float* __restrict__ hidden,
                                               const float* __restrict__ W,
                                               const float* __restrict__ bias,
                                               float* __restrict__ em,
                                               unsigned int* __restrict__ flags,
                                               float* __restrict__ vglob,
                                               const int* __restrict__ label,
                                               const int* __restrict__ mask,
                                               const float* __restrict__ startT,
                                               const float* __restrict__ endT,
                                               const float* __restrict__ trans,
                                               float* __restrict__ out) {
    __shared__ float s_part[4][4][NL];
    __shared__ float s_T[NL * NL];
    __shared__ int s_mki[4][NS];
    __shared__ unsigned char s_bp[4 * BPST];
    __shared__ unsigned char s_path[4 * NS];

    int bx = blockIdx.x;
    int tid = threadIdx.x;
    int lane = tid & 63;

    if (bx < NGEMM) {
        // ---------------- GEMM role (R0-proven body, t-major block order) ----------
        int w = tid >> 6;
        int tq = bx >> 6;                 // t-group: covers t = 4tq..4tq+3
        int b  = bx & 63;                 // batch
        int kbase = 192 * w + lane;
        float Wv[3][NL];
#pragma unroll
        for (int c = 0; c < 3; c++) {
            const float* wp = W + (size_t)(kbase + 64 * c) * NL;
#pragma unroll
            for (int j = 0; j < NL; j++) Wv[c][j] = wp[j];
        }
#pragma unroll
        for (int r = 0; r < 4; r++) {
            int row = b * NS + 4 * tq + r;
            const float* hp = hidden + (size_t)row * NH + kbase;
            float h0 = hp[0], h1 = hp[64], h2 = hp[128];
            float acc[NL];
#pragma unroll
            for (int j = 0; j < NL; j++) {
                acc[j] = fmaf(h0, Wv[0][j], fmaf(h1, Wv[1][j], h2 * Wv[2][j]));
            }
#pragma unroll
            for (int j = 0; j < NL; j++) acc[j] = wave_sum_to63(acc[j]);
            if (lane == 63) {
#pragma unroll
                for (int j = 0; j < NL; j++) s_part[w][r][j] = acc[j];
            }
        }
        __syncthreads();
        if (tid < 36) {
            int r = tid / NL, j = tid % NL;
            float v = (s_part[0][r][j] + s_part[1][r][j]) +
                      (s_part[2][r][j] + s_part[3][r][j]) + bias[j];
            em[(size_t)(b * NS + 4 * tq + r) * NL + j] = v;
        }
        // release: drain stores (threadfence waits vmcnt + wbL2), then flag.
        if (tid == 0) {
            __threadfence();
            atomicAdd(&flags[b * 16 + (tq >> 3)], 1u);
        }
        return;
    }

    // ---------------- DP role (R2-proven trees + chunk gating) ----------------
    int dpb = bx - NGEMM;
    bool isfwd = dpb < 16;
    int b0 = (isfwd ? dpb : (dpb - 16)) * 4;

    if (tid < NL * NL) s_T[tid] = trans[tid];
    if (isfwd) {
        for (int q = tid; q < 4 * NS / 4; q += 256)
            ((int4*)s_mki)[q] = ((const int4*)(mask + b0 * NS))[q];
    }
    __syncthreads();

    if (isfwd) {
        if (tid < 64) {
            // ---- forward chain, 4 batches (one per 16-lane row), gated ----
            int bb = lane >> 4;
            int jcol = lane & 15;
            int jcol9 = jcol < NL ? jcol : NL - 1;
            unsigned int* fbase = flags + (size_t)(b0 + bb) * 16;
            poll8(fbase + 0);
            __threadfence();
            const float* gp = em + (size_t)(b0 + bb) * (NS * NL) + jcol9;
            float Mc0 = __expf(s_T[0 * NL + jcol9]);
            float Mc1 = __expf(s_T[1 * NL + jcol9]);
            float Mc2 = __expf(s_T[2 * NL + jcol9]);
            float Mc3 = __expf(s_T[3 * NL + jcol9]);
            float Mc4 = __expf(s_T[4 * NL + jcol9]);
            float Mc5 = __expf(s_T[5 * NL + jcol9]);
            float Mc6 = __expf(s_T[6 * NL + jcol9]);
            float Mc7 = __expf(s_T[7 * NL + jcol9]);
            float Mc8 = __expf(s_T[8 * NL + jcol9]);
            float a = __expf(startT[jcol9] + gp[0]);
            int eacc = 0;

#define FBODY(EC_, KC_) do { \
    float _w0=rowbc<0>(a),_w1=rowbc<1>(a),_w2=rowbc<2>(a),_w3=rowbc<3>(a),_w4=rowbc<4>(a), \
          _w5=rowbc<5>(a),_w6=rowbc<6>(a),_w7=rowbc<7>(a),_w8=rowbc<8>(a); \
    float _p0=_w0*Mc0,_p1=_w1*Mc1,_p2=_w2*Mc2,_p3=_w3*Mc3,_p4=_w4*Mc4, \
          _p5=_w5*Mc5,_p6=_w6*Mc6,_p7=_w7*Mc7,_p8=_w8*Mc8; \
    float _s=(((_p0+_p1)+(_p2+_p3))+((_p4+_p5)+(_p6+_p7)))+_p8; \
    float _an=(EC_)*_s; \
    a = ((KC_) > 0) ? _an : a; \
} while (0)

#define FREN() do { \
    float _c0=rowbc<0>(a),_c1=rowbc<1>(a),_c2=rowbc<2>(a),_c3=rowbc<3>(a),_c4=rowbc<4>(a), \
          _c5=rowbc<5>(a),_c6=rowbc<6>(a),_c7=rowbc<7>(a),_c8=rowbc<8>(a); \
    float _cc=(((_c0+_c1)+(_c2+_c3))+((_c4+_c5)+(_c6+_c7)))+_c8; \
    int _ex=((__float_as_int(_cc)>>23)&255)-127; \
    a=ldexpf(a,-_ex); eacc+=_ex; \
} while (0)

            float e8[8]; int k8[8];
#pragma unroll
            for (int p = 0; p < 8; p++) {
                e8[p] = __expf(gp[(1 + p) * NL]);
                k8[p] = s_mki[bb][1 + p];
            }
            int ready = 0;
            for (int t0 = 1; t0 <= NS - 15; t0 += 8) {
                int cneed = (t0 + 15) >> 5; cneed = cneed > 15 ? 15 : cneed;
                if (cneed != ready) { poll8(fbase + cneed); __threadfence(); ready = cneed; }
#pragma unroll
                for (int p = 0; p < 8; p++) {
                    int t = t0 + p;
                    float ec = e8[p]; int kc = k8[p];
                    int tn = t + 8; tn = tn > NS - 1 ? NS - 1 : tn;
                    e8[p] = __expf(gp[tn * NL]);
                    k8[p] = s_mki[bb][tn];
                    FBODY(ec, kc);
                    if (p == 7) FREN();
                }
            }
#pragma unroll
            for (int p = 0; p < 7; p++) FBODY(e8[p], k8[p]);
#undef FBODY
#undef FREN
            float z = a * __expf(endT[jcol9]);
            float c0 = rowbc<0>(z), c1 = rowbc<1>(z), c2 = rowbc<2>(z);
            float c3 = rowbc<3>(z), c4 = rowbc<4>(z), c5 = rowbc<5>(z);
            float c6 = rowbc<6>(z), c7 = rowbc<7>(z), c8 = rowbc<8>(z);
            float c = (((c0 + c1) + (c2 + c3)) + ((c4 + c5) + (c6 + c7))) + c8;
            if (jcol == 0) {
                float lz = (float)eacc * 0.6931471805599453f + __logf(c);
                atomicAdd(out, lz * (1.0f / (float)NB));
            }
        } else if (tid < 128) {
            // ---- numerator, gated on full batch ----
            int g = lane >> 4;
            int ll = lane & 15;
            int b = b0 + g;
            unsigned int* fbase = flags + (size_t)b * 16;
            for (int c = 0; c < 16; c++) poll8(fbase + c);
            __threadfence();
            const int* lb = label + b * NS;
            const float* ge = em + (size_t)b * NS * NL;
            int h = 0, sl = 0;
            for (int cch = 0; cch < 4; cch++) {
                int la8[8]; int mk8[8];
#pragma unroll
                for (int r = 0; r < 8; r++) {
                    int t = ll * 32 + cch * 8 + r;
                    la8[r] = lb[t];
                    int m = s_mki[g][t];
                    if (t == 0) m = 1;
                    mk8[r] = m;
                }
#pragma unroll
                for (int r = 0; r < 8; r++) if (mk8[r] > 0) { h = 1; sl = la8[r]; }
            }
#pragma unroll
            for (int d = 1; d < 16; d <<= 1) {
                int ho = __shfl_up(h, d, 16);
                int so = __shfl_up(sl, d, 16);
                if (!h) { h = ho; sl = so; }
            }
            int lg = __shfl(sl, 15, 16);
            int incoming = __shfl_up(sl, 1, 16);
            int labz = lb[0];
            int prevr = (ll == 0) ? labz : incoming;
            float sc = 0.f;
            for (int cch = 0; cch < 4; cch++) {
                int la8[8]; int mk8[8]; float ev8[8];
#pragma unroll
                for (int r = 0; r < 8; r++) {
                    int t = ll * 32 + cch * 8 + r;
                    la8[r] = lb[t];
                    int m = s_mki[g][t];
                    if (t == 0) m = 1;
                    mk8[r] = m;
                }
#pragma unroll
                for (int r = 0; r < 8; r++) {
                    int t = ll * 32 + cch * 8 + r;
                    ev8[r] = ge[t * NL + la8[r]];
                }
#pragma unroll
                for (int r = 0; r < 8; r++) {
                    int t = ll * 32 + cch * 8 + r;
                    if (t > 0) {
                        float s = s_T[prevr * NL + la8[r]] + ev8[r];
                        sc += s * (float)mk8[r];
                    }
                    if (mk8[r] > 0) prevr = la8[r];
                }
            }
            if (ll == 0) sc += startT[labz] + ge[labz] + endT[lg];
#pragma unroll
            for (int d = 1; d < 16; d <<= 1) sc += __shfl_xor(sc, d, 16);
            if (ll == 0) atomicAdd(out, -sc * (1.0f / (float)NB));
        }
    } else {
        // ---- Viterbi chain (v-history in GLOBAL vglob), gated ----
        if (tid < 64) {
            int bb = lane >> 4;
            int jcol = lane & 15;
            int jcol9 = jcol < NL ? jcol : NL - 1;
            unsigned int* fbase = flags + (size_t)(b0 + bb) * 16;
            poll8(fbase + 0);
            __threadfence();
            const float* gv = em + (size_t)(b0 + bb) * (NS * NL) + jcol9;
            float* vg = vglob + (size_t)(b0 + bb) * VST;
            float Tc0 = s_T[0 * NL + jcol9];
            float Tc1 = s_T[1 * NL + jcol9];
            float Tc2 = s_T[2 * NL + jcol9];
            float Tc3 = s_T[3 * NL + jcol9];
            float Tc4 = s_T[4 * NL + jcol9];
            float Tc5 = s_T[5 * NL + jcol9];
            float Tc6 = s_T[6 * NL + jcol9];
            float Tc7 = s_T[7 * NL + jcol9];
            float Tc8 = s_T[8 * NL + jcol9];
            float v = startT[jcol9] + gv[0];
            if (jcol < NL) vg[jcol] = v;   // t = 0 (masked: global stores unordered)

#define VBODY(EC_, T_) do { \
    float _w0=rowbc<0>(v),_w1=rowbc<1>(v),_w2=rowbc<2>(v),_w3=rowbc<3>(v),_w4=rowbc<4>(v), \
          _w5=rowbc<5>(v),_w6=rowbc<6>(v),_w7=rowbc<7>(v),_w8=rowbc<8>(v); \
    float _m0=_w0+Tc0,_m1=_w1+Tc1,_m2=_w2+Tc2,_m3=_w3+Tc3,_m4=_w4+Tc4, \
          _m5=_w5+Tc5,_m6=_w6+Tc6,_m7=_w7+Tc7,_m8=_w8+Tc8; \
    float _Ma=fmaxf(fmaxf(_m0,_m1),_m2); \
    float _Mb=fmaxf(fmaxf(_m3,_m4),_m5); \
    float _Mc=fmaxf(fmaxf(_m6,_m7),_m8); \
    v = fmaxf(fmaxf(_Ma,_Mb),_Mc) + (EC_); \
    if (jcol < NL) vg[(T_) * NL + jcol] = v; \
} while (0)

            float e8[8];
#pragma unroll
            for (int p = 0; p < 8; p++) e8[p] = gv[(1 + p) * NL];
            int ready = 0;
            for (int t0 = 1; t0 <= NS - 15; t0 += 8) {
                int cneed = (t0 + 15) >> 5; cneed = cneed > 15 ? 15 : cneed;
                if (cneed != ready) { poll8(fbase + cneed); __threadfence(); ready = cneed; }
#pragma unroll
                for (int p = 0; p < 8; p++) {
                    int t = t0 + p;
                    float ec = e8[p];
                    int tn = t + 8; tn = tn > NS - 1 ? NS - 1 : tn;
                    e8[p] = gv[tn * NL];
                    VBODY(ec, t);
                }
            }
#pragma unroll
            for (int p = 0; p < 7; p++) VBODY(e8[p], 505 + p);
#undef VBODY
        }
        __syncthreads();
        __threadfence();   // per-wave acquire before block-wide em/vglob reads
        // ---- phase 2: backpointers (exact ref op order) ----
        for (int it = 0; it < 8; it++) {
            int item = tid + it * 256;
            int bb = item >> 9;
            int t = item & (NS - 1);
            if (t > 0) {
                const float* vpp = vglob + (size_t)(b0 + bb) * VST + (t - 1) * NL;
                const float* ge = em + (size_t)(b0 + bb) * (NS * NL) + t * NL;
                float vp[NL], emt[NL];
#pragma unroll
                for (int i = 0; i < NL; i++) vp[i] = vpp[i];
#pragma unroll
                for (int j = 0; j < NL; j++) emt[j] = ge[j];
#pragma unroll
                for (int j = 0; j < NL; j++) {
                    float e = emt[j];
                    float val[NL];
#pragma unroll
                    for (int i = 0; i < NL; i++) val[i] = (vp[i] + s_T[i * NL + j]) + e;
                    bool c01 = val[0] >= val[1]; float m01 = c01 ? val[0] : val[1]; int i01 = c01 ? 0 : 1;
                    bool c23 = val[2] >= val[3]; float m23 = c23 ? val[2] : val[3]; int i23 = c23 ? 2 : 3;
                    bool c45 = val[4] >= val[5]; float m45 = c45 ? val[4] : val[5]; int i45 = c45 ? 4 : 5;
                    bool c67 = val[6] >= val[7]; float m67 = c67 ? val[6] : val[7]; int i67 = c67 ? 6 : 7;
                    bool ca = m01 >= m23; float ma = ca ? m01 : m23; int ia = ca ? i01 : i23;
                    bool cb = m45 >= m67; float mb = cb ? m45 : m67; int ib = cb ? i45 : i67;
                    bool cc = ma >= mb;  float mc = cc ? ma : mb;  int ic = cc ? ia : ib;
                    bool cd = mc >= val[8]; int bi = cd ? ic : 8;
                    s_bp[bb * BPST + t * NL + j] = (unsigned char)bi;
                }
            }
        }
        __syncthreads();
        // ---- phase 3: last tag + map-composition backtrack (wave w -> batch w) ----
        {
            int w = tid >> 6;
            const float* sv = vglob + (size_t)(b0 + w) * VST;
            const unsigned char* bpp = s_bp + w * BPST;
            unsigned char* pth = s_path + w * NS;
            float bb2 = sv[(NS - 1) * NL + 0] + endT[0]; int lt = 0;
#pragma unroll
            for (int jj = 1; jj < NL; jj++) {
                float fj = sv[(NS - 1) * NL + jj] + endT[jj];
                if (fj > bb2) { bb2 = fj; lt = jj; }
            }
            unsigned long long G[8];
#pragma unroll
            for (int r = 0; r < 8; r++) {
                int t0 = (lane * 8 + r) * NL;
                unsigned long long g = 0;
                if (lane == 0 && r == 0) {
                    g = 0x876543210ULL;
                } else {
#pragma unroll
                    for (int x = 0; x < NL; x++) g |= (unsigned long long)bpp[t0 + x] << (4 * x);
                }
                G[r] = g;
            }
            unsigned long long A = 0x876543210ULL;
#pragma unroll
            for (int r = 7; r >= 0; r--) {
                unsigned long long An = 0;
#pragma unroll
                for (int x = 0; x < NL; x++) {
                    int ax = (int)((A >> (4 * x)) & 15ULL);
                    int gvv = (int)((G[r] >> (4 * ax)) & 15ULL);
                    An |= (unsigned long long)gvv << (4 * x);
                }
                A = An;
            }
            int e = 0; int cur = lt;
            for (int llv = 63; llv >= 0; --llv) {
                if (lane == llv) e = cur;
                unsigned long long Al = readlane_u64(A, llv);
                cur = (int)((Al >> (4 * cur)) & 15ULL);
            }
            unsigned long long pw = 0; int c2 = e;
#pragma unroll
            for (int r = 7; r >= 0; r--) {
                pw |= (unsigned long long)c2 << (8 * r);
                c2 = (int)((G[r] >> (4 * c2)) & 15ULL);
            }
            *(unsigned long long*)(pth + lane * 8) = pw;
        }
        __syncthreads();
        // ---- finalize ----
        float cnt = 0.f;
#pragma unroll
        for (int q = 0; q < 8; q++) {
            int item = tid + q * 256;
            int bb = item >> 9;
            int t = item & (NS - 1);
            int b = b0 + bb;
            int idx = b * NS + t;
            int lab = label[idx];
            int p = (int)s_path[bb * NS + t];
            int pred = (lab > 0) ? p : 0;
            out[2 + idx] = (float)pred;
            out[2 + NROWS + idx] = (float)lab;
            cnt += (pred == lab) ? 1.f : 0.f;
        }
#pragma unroll
        for (int d = 1; d < 64; d <<= 1) cnt += __shfl_xor(cnt, d);
        if ((tid & 63) == 0) atomicAdd(out + 1, cnt);
    }
}

// =====================================================================
// FALLBACK path (ws too small): R2-exact two-kernel pipeline
// =====================================================================
__global__ __launch_bounds__(256) void k_gemm(const float* __restrict__ hidden,
                                              const float* __restrict__ W,
                                              const float* __restrict__ bias,
                                              float* __restrict__ em,
                                              float* __restrict__ out) {
    __shared__ float s_part[4][4][NL];
    int tid = threadIdx.x;
    int lane = tid & 63;
    int w = tid >> 6;
    int bx = blockIdx.x;
    if (bx == 0 && tid == 0) { out[0] = 0.f; out[1] = 0.f; }
    int kbase = 192 * w + lane;
    float Wv[3][NL];
#pragma unroll
    for (int c = 0; c < 3; c++) {
        const float* wp = W + (size_t)(kbase + 64 * c) * NL;
#pragma unroll
        for (int j = 0; j < NL; j++) Wv[c][j] = wp[j];
    }
#pragma unroll
    for (int r = 0; r < 4; r++) {
        int row = 4 * bx + r;
        const float* hp = hidden + (size_t)row * NH + kbase;
        float h0 = hp[0], h1 = hp[64], h2 = hp[128];
        float acc[NL];
#pragma unroll
        for (int j = 0; j < NL; j++) {
            acc[j] = fmaf(h0, Wv[0][j], fmaf(h1, Wv[1][j], h2 * Wv[2][j]));
        }
#pragma unroll
        for (int j = 0; j < NL; j++) acc[j] = wave_sum_to63(acc[j]);
        if (lane == 63) {
#pragma unroll
            for (int j = 0; j < NL; j++) s_part[w][r][j] = acc[j];
        }
    }
    __syncthreads();
    if (tid < 36) {
        int r = tid / NL, j = tid % NL;
        float v = (s_part[0][r][j] + s_part[1][r][j]) +
                  (s_part[2][r][j] + s_part[3][r][j]) + bias[j];
        em[(size_t)(4 * bx + r) * NL + j] = v;
    }
}

__global__ __launch_bounds__(256) void k_dp(const float* __restrict__ em,
                                            const int* __restrict__ label,
                                            const int* __restrict__ mask,
                                            const float* __restrict__ startT,
                                            const float* __restrict__ endT,
                                            const float* __restrict__ trans,
                                            float* __restrict__ out) {
    __shared__ float s_T[NL * NL];
    __shared__ int s_mki[4][NS];
    __shared__ float s_v[4 * VST];
    __shared__ unsigned char s_bp[4 * BPST];
    __shared__ unsigned char s_path[4 * NS];

    int bx = blockIdx.x;
    int tid = threadIdx.x;
    int lane = tid & 63;
    bool isfwd = bx < 16;
    int b0 = (isfwd ? bx : (bx - 16)) * 4;

    if (tid < NL * NL) s_T[tid] = trans[tid];
    if (isfwd) {
        for (int q = tid; q < 4 * NS / 4; q += 256)
            ((int4*)s_mki)[q] = ((const int4*)(mask + b0 * NS))[q];
    }
    __syncthreads();

    if (isfwd) {
        if (tid < 64) {
            int bb = lane >> 4;
            int jcol = lane & 15;
            int jcol9 = jcol < NL ? jcol : NL - 1;
            const float* gp = em + (size_t)(b0 + bb) * (NS * NL) + jcol9;
            float Mc0 = __expf(s_T[0 * NL + jcol9]);
            float Mc1 = __expf(s_T[1 * NL + jcol9]);
            float Mc2 = __expf(s_T[2 * NL + jcol9]);
            float Mc3 = __expf(s_T[3 * NL + jcol9]);
            float Mc4 = __expf(s_T[4 * NL + jcol9]);
            float Mc5 = __expf(s_T[5 * NL + jcol9]);
            float Mc6 = __expf(s_T[6 * NL + jcol9]);
            float Mc7 = __expf(s_T[7 * NL + jcol9]);
            float Mc8 = __expf(s_T[8 * NL + jcol9]);
            float a = __expf(startT[jcol9] + gp[0]);
            int eacc = 0;
#define FBODY(EC_, KC_) do { \
    float _w0=rowbc<0>(a),_w1=rowbc<1>(a),_w2=rowbc<2>(a),_w3=rowbc<3>(a),_w4=rowbc<4>(a), \
          _w5=rowbc<5>(a),_w6=rowbc<6>(a),_w7=rowbc<7>(a),_w8=rowbc<8>(a); \
    float _p0=_w0*Mc0,_p1=_w1*Mc1,_p2=_w2*Mc2,_p3=_w3*Mc3,_p4=_w4*Mc4, \
          _p5=_w5*Mc5,_p6=_w6*Mc6,_p7=_w7*Mc7,_p8=_w8*Mc8; \
    float _s=(((_p0+_p1)+(_p2+_p3))+((_p4+_p5)+(_p6+_p7)))+_p8; \
    float _an=(EC_)*_s; \
    a = ((KC_) > 0) ? _an : a; \
} while (0)
#define FREN() do { \
    float _c0=rowbc<0>(a),_c1=rowbc<1>(a),_c2=rowbc<2>(a),_c3=rowbc<3>(a),_c4=rowbc<4>(a), \
          _c5=rowbc<5>(a),_c6=rowbc<6>(a),_c7=rowbc<7>(a),_c8=rowbc<8>(a); \
    float _cc=(((_c0+_c1)+(_c2+_c3))+((_c4+_c5)+(_c6+_c7)))+_c8; \
    int _ex=((__float_as_int(_cc)>>23)&255)-127; \
    a=ldexpf(a,-_ex); eacc+=_ex; \
} while (0)
            float e8[8]; int k8[8];
#pragma unroll
            for (int p = 0; p < 8; p++) {
                e8[p] = __expf(gp[(1 + p) * NL]);
                k8[p] = s_mki[bb][1 + p];
            }
            for (int t0 = 1; t0 <= NS - 15; t0 += 8) {
#pragma unroll
                for (int p = 0; p < 8; p++) {
                    int t = t0 + p;
                    float ec = e8[p]; int kc = k8[p];
                    int tn = t + 8; tn = tn > NS - 1 ? NS - 1 : tn;
                    e8[p] = __expf(gp[tn * NL]);
                    k8[p] = s_mki[bb][tn];
                    FBODY(ec, kc);
                    if (p == 7) FREN();
                }
            }
#pragma unroll
            for (int p = 0; p < 7; p++) FBODY(e8[p], k8[p]);
#undef FBODY
#undef FREN
            float z = a * __expf(endT[jcol9]);
            float c0 = rowbc<0>(z), c1 = rowbc<1>(z), c2 = rowbc<2>(z);
            float c3 = rowbc<3>(z), c4 = rowbc<4>(z), c5 = rowbc<5>(z);
            float c6 = rowbc<6>(z), c7 = rowbc<7>(z), c8 = rowbc<8>(z);
            float c = (((c0 + c1) + (c2 + c3)) + ((c4 + c5) + (c6 + c7))) + c8;
            if (jcol == 0) {
                float lz = (float)eacc * 0.6931471805599453f + __logf(c);
                atomicAdd(out, lz * (1.0f / (float)NB));
            }
        } else if (tid < 128) {
            int g = lane >> 4;
            int ll = lane & 15;
            int b = b0 + g;
            const int* lb = label + b * NS;
            const float* ge = em + (size_t)b * NS * NL;
            int h = 0, sl = 0;
            for (int cch = 0; cch < 4; cch++) {
                int la8[8]; int mk8[8];
#pragma unroll
                for (int r = 0; r < 8; r++) {
                    int t = ll * 32 + cch * 8 + r;
                    la8[r] = lb[t];
                    int m = s_mki[g][t];
                    if (t == 0) m = 1;
                    mk8[r] = m;
                }
#pragma unroll
                for (int r = 0; r < 8; r++) if (mk8[r] > 0) { h = 1; sl = la8[r]; }
            }
#pragma unroll
            for (int d = 1; d < 16; d <<= 1) {
                int ho = __shfl_up(h, d, 16);
                int so = __shfl_up(sl, d, 16);
                if (!h) { h = ho; sl = so; }
            }
            int lg = __shfl(sl, 15, 16);
            int incoming = __shfl_up(sl, 1, 16);
            int labz = lb[0];
            int prevr = (ll == 0) ? labz : incoming;
            float sc = 0.f;
            for (int cch = 0; cch < 4; cch++) {
                int la8[8]; int mk8[8]; float ev8[8];
#pragma unroll
                for (int r = 0; r < 8; r++) {
                    int t = ll * 32 + cch * 8 + r;
                    la8[r] = lb[t];
                    int m = s_mki[g][t];
                    if (t == 0) m = 1;
                    mk8[r] = m;
                }
#pragma unroll
                for (int r = 0; r < 8; r++) {
                    int t = ll * 32 + cch * 8 + r;
                    ev8[r] = ge[t * NL + la8[r]];
                }
#pragma unroll
                for (int r = 0; r < 8; r++) {
                    int t = ll * 32 + cch * 8 + r;
                    if (t > 0) {
                        float s = s_T[prevr * NL + la8[r]] + ev8[r];
                        sc += s * (float)mk8[r];
                    }
                    if (mk8[r] > 0) prevr = la8[r];
                }
            }
            if (ll == 0) sc += startT[labz] + ge[labz] + endT[lg];
#pragma unroll
            for (int d = 1; d < 16; d <<= 1) sc += __shfl_xor(sc, d, 16);
            if (ll == 0) atomicAdd(out, -sc * (1.0f / (float)NB));
        }
    } else {
        if (tid < 64) {
            int bb = lane >> 4;
            int jcol = lane & 15;
            int jcol9 = jcol < NL ? jcol : NL - 1;
            const float* gv = em + (size_t)(b0 + bb) * (NS * NL) + jcol9;
            float Tc0 = s_T[0 * NL + jcol9];
            float Tc1 = s_T[1 * NL + jcol9];
            float Tc2 = s_T[2 * NL + jcol9];
            float Tc3 = s_T[3 * NL + jcol9];
            float Tc4 = s_T[4 * NL + jcol9];
            float Tc5 = s_T[5 * NL + jcol9];
            float Tc6 = s_T[6 * NL + jcol9];
            float Tc7 = s_T[7 * NL + jcol9];
            float Tc8 = s_T[8 * NL + jcol9];
            float v = startT[jcol9] + gv[0];
            int svbase = bb * VST + jcol;
            s_v[svbase] = v;
#define VBODY(EC_, T_) do { \
    float _w0=rowbc<0>(v),_w1=rowbc<1>(v),_w2=rowbc<2>(v),_w3=rowbc<3>(v),_w4=rowbc<4>(v), \
          _w5=rowbc<5>(v),_w6=rowbc<6>(v),_w7=rowbc<7>(v),_w8=rowbc<8>(v); \
    float _m0=_w0+Tc0,_m1=_w1+Tc1,_m2=_w2+Tc2,_m3=_w3+Tc3,_m4=_w4+Tc4, \
          _m5=_w5+Tc5,_m6=_w6+Tc6,_m7=_w7+Tc7,_m8=_w8+Tc8; \
    float _Ma=fmaxf(fmaxf(_m0,_m1),_m2); \
    float _Mb=fmaxf(fmaxf(_m3,_m4),_m5); \
    float _Mc=fmaxf(fmaxf(_m6,_m7),_m8); \
    v = fmaxf(fmaxf(_Ma,_Mb),_Mc) + (EC_); \
    s_v[svbase + (T_) * NL] = v; \
} while (0)
            float e8[8];
#pragma unroll
            for (int p = 0; p < 8; p++) e8[p] = gv[(1 + p) * NL];
            for (int t0 = 1; t0 <= NS - 15; t0 += 8) {
#pragma unroll
                for (int p = 0; p < 8; p++) {
                    int t = t0 + p;
                    float ec = e8[p];
                    int tn = t + 8; tn = tn > NS - 1 ? NS - 1 : tn;
                    e8[p] = gv[tn * NL];
                    VBODY(ec, t);
                }
            }
#pragma unroll
            for (int p = 0; p < 7; p++) VBODY(e8[p], 505 + p);
#undef VBODY
        }
        __syncthreads();
        for (int it = 0; it < 8; it++) {
            int item = tid + it * 256;
            int bb = item >> 9;
            int t = item & (NS - 1);
            if (t > 0) {
                const float* vpp = s_v + bb * VST + (t - 1) * NL;
                const float* ge = em + (size_t)(b0 + bb) * (NS * NL) + t * NL;
                float vp[NL], emt[NL];
#pragma unroll
                for (int i = 0; i < NL; i++) vp[i] = vpp[i];
#pragma unroll
                for (int j = 0; j < NL; j++) emt[j] = ge[j];
#pragma unroll
                for (int j = 0; j < NL; j++) {
                    float e = emt[j];
                    float val[NL];
#pragma unroll
                    for (int i = 0; i < NL; i++) val[i] = (vp[i] + s_T[i * NL + j]) + e;
                    bool c01 = val[0] >= val[1]; float m01 = c01 ? val[0] : val[1]; int i01 = c01 ? 0 : 1;
                    bool c23 = val[2] >= val[3]; float m23 = c23 ? val[2] : val[3]; int i23 = c23 ? 2 : 3;
                    bool c45 = val[4] >= val[5]; float m45 = c45 ? val[4] : val[5]; int i45 = c45 ? 4 : 5;
                    bool c67 = val[6] >= val[7]; float m67 = c67 ? val[6] : val[7]; int i67 = c67 ? 6 : 7;
                    bool ca = m01 >= m23; float ma = ca ? m01 : m23; int ia = ca ? i01 : i23;
                    bool cb = m45 >= m67; float mb = cb ? m45 : m67; int ib = cb ? i45 : i67;
                    bool cc = ma >= mb;  float mc = cc ? ma : mb;  int ic = cc ? ia : ib;
                    bool cd = mc >= val[8]; int bi = cd ? ic : 8;
                    s_bp[bb * BPST + t * NL + j] = (unsigned char)bi;
                }
            }
        }
        __syncthreads();
        {
            int w = tid >> 6;
            const float* sv = s_v + w * VST;
            const unsigned char* bpp = s_bp + w * BPST;
            unsigned char* pth = s_path + w * NS;
            float bb2 = sv[(NS - 1) * NL + 0] + endT[0]; int lt = 0;
#pragma unroll
            for (int jj = 1; jj < NL; jj++) {
                float fj = sv[(NS - 1) * NL + jj] + endT[jj];
                if (fj > bb2) { bb2 = fj; lt = jj; }
            }
            unsigned long long G[8];
#pragma unroll
            for (int r = 0; r < 8; r++) {
                int t0 = (lane * 8 + r) * NL;
                unsigned long long g = 0;
                if (lane == 0 && r == 0) {
                    g = 0x876543210ULL;
                } else {
#pragma unroll
                    for (int x = 0; x < NL; x++) g |= (unsigned long long)bpp[t0 + x] << (4 * x);
                }
                G[r] = g;
            }
            unsigned long long A = 0x876543210ULL;
#pragma unroll
            for (int r = 7; r >= 0; r--) {
                unsigned long long An = 0;
#pragma unroll
                for (int x = 0; x < NL; x++) {
                    int ax = (int)((A >> (4 * x)) & 15ULL);
                    int gvv = (int)((G[r] >> (4 * ax)) & 15ULL);
                    An |= (unsigned long long)gvv << (4 * x);
                }
                A = An;
            }
            int e = 0; int cur = lt;
            for (int llv = 63; llv >= 0; --llv) {
                if (lane == llv) e = cur;
                unsigned long long Al = readlane_u64(A, llv);
                cur = (int)((Al >> (4 * cur)) & 15ULL);
            }
            unsigned long long pw = 0; int c2 = e;
#pragma unroll
            for (int r = 7; r >= 0; r--) {
                pw |= (unsigned long long)c2 << (8 * r);
                c2 = (int)((G[r] >> (4 * c2)) & 15ULL);
            }
            *(unsigned long long*)(pth + lane * 8) = pw;
        }
        __syncthreads();
        float cnt = 0.f;
#pragma unroll
        for (int q = 0; q < 8; q++) {
            int item = tid + q * 256;
            int bb = item >> 9;
            int t = item & (NS - 1);
            int b = b0 + bb;
            int idx = b * NS + t;
            int lab = label[idx];
            int p = (int)s_path[bb * NS + t];
            int pred = (lab > 0) ? p : 0;
            out[2 + idx] = (float)pred;
            out[2 + NROWS + idx] = (float)lab;
            cnt += (pred == lab) ? 1.f : 0.f;
        }
#pragma unroll
        for (int d = 1; d < 64; d <<= 1) cnt += __shfl_xor(cnt, d);
        if ((tid & 63) == 0) atomicAdd(out + 1, cnt);
    }
}

extern "C" void kernel_launch(void* const* d_in, const int* in_sizes, int n_in,
                              void* d_out, int out_size, void* d_ws, size_t ws_size,
                              hipStream_t stream) {
    const float* hidden = (const float*)d_in[0];
    const int*   label  = (const int*)d_in[1];
    const int*   mask   = (const int*)d_in[2];
    const float* W      = (const float*)d_in[3];
    const float* bias   = (const float*)d_in[4];
    const float* startT = (const float*)d_in[5];
    const float* endT   = (const float*)d_in[6];
    const float* trans  = (const float*)d_in[7];
    float* out = (float*)d_out;

    float* em = (float*)d_ws;                                   // EMN floats
    unsigned int* flags = (unsigned int*)(em + EMN);            // 64*16 u32 = 4KB
    float* vglob = (float*)((char*)flags + 4096);               // 64*VST floats
    size_t need = (size_t)EMN * 4 + 4096 + (size_t)64 * VST * 4;

    if (ws_size >= need) {
        hipMemsetAsync(flags, 0, 4096, stream);
        hipMemsetAsync(d_out, 0, 8, stream);                    // out[0], out[1]
        k_fused<<<NGEMM + 32, 256, 0, stream>>>(hidden, W, bias, em, flags, vglob,
                                                label, mask, startT, endT, trans, out);
    } else {
        k_gemm<<<8192, 256, 0, stream>>>(hidden, W, bias, em, out);
        k_dp<<<32, 256, 0, stream>>>(em, label, mask, startT, endT, trans, out);
    }
}

// Round 7
// 273.272 us; speedup vs baseline: 2.0547x; 2.0547x over previous
//
#include <hip/hip_runtime.h>
#include <hip/hip_bf16.h>

// Problem constants: B=64, S=512, H=768, L=9
#define NB 64
#define NS 512
#define NH 768
#define NL 9
#define NROWS (NB*NS)          // 32768
#define EMN (NROWS*NL)         // 294912

// per-batch LDS strides (padded off %32==0)
#define VST  4617              // floats per batch for s_v
#define BPST 4616              // bytes  per batch for s_bp

__device__ __forceinline__ unsigned long long readlane_u64(unsigned long long v, int l) {
    unsigned int lo = (unsigned int)__builtin_amdgcn_readlane((int)(unsigned int)(v & 0xffffffffULL), l);
    unsigned int hi = (unsigned int)__builtin_amdgcn_readlane((int)(unsigned int)(v >> 32), l);
    return ((unsigned long long)hi << 32) | (unsigned long long)lo;
}
template <int CTRL>
__device__ __forceinline__ float dpp_add(float x) {
    int t = __builtin_amdgcn_update_dpp(0, __float_as_int(x), CTRL, 0xf, 0xf, false);
    return x + __int_as_float(t);
}
__device__ __forceinline__ float wave_sum_to63(float x) {
    x = dpp_add<0x111>(x);  // row_shr:1
    x = dpp_add<0x112>(x);  // row_shr:2
    x = dpp_add<0x114>(x);  // row_shr:4
    x = dpp_add<0x118>(x);  // row_shr:8
    x = dpp_add<0x142>(x);  // row_bcast:15
    x = dpp_add<0x143>(x);  // row_bcast:31 -> lane63 = wave sum
    return x;
}
// quad_perm broadcast: every lane of a 4-lane quad receives lane Q's value.
// DPP quad_perm ctrl = Q | Q<<2 | Q<<4 | Q<<6. Pure VALU (no LDS pipe).
template <int CTRL>
__device__ __forceinline__ float qperm(float x) {
    return __int_as_float(__builtin_amdgcn_update_dpp(0, __float_as_int(x), CTRL, 0xf, 0xf, false));
}

// ---------------- Kernel A: emissions GEMM v3 (persistent W, grid-stride) --------
// 1024 blocks x 256 thr, ALL co-resident (4 blocks/CU): zero block turnover.
// Each block: W preload ONCE (27 regs/lane, L2 W traffic 226MB -> 28MB), then 8
// row-groups of 4 rows with next-group hidden prefetched into registers (the
// load->compute serial chain that started every one of the old 8192 blocks is
// now hidden under the previous group's compute). Per-row FMA + wave_sum tree +
// 4-wave combine are VERBATIM from the proven kernel -> bit-identical em.
__global__ __launch_bounds__(256) void k_gemm(const float* __restrict__ hidden,
                                              const float* __restrict__ W,
                                              const float* __restrict__ bias,
                                              float* __restrict__ em,
                                              float* __restrict__ out) {
    __shared__ float s_part[4][4][NL];
    int tid = threadIdx.x;
    int lane = tid & 63;
    int w = tid >> 6;
    int bx = blockIdx.x;
    if (bx == 0 && tid == 0) { out[0] = 0.f; out[1] = 0.f; }

    int kbase = 192 * w + lane;
    float Wv[3][NL];
#pragma unroll
    for (int c = 0; c < 3; c++) {
        const float* wp = W + (size_t)(kbase + 64 * c) * NL;
#pragma unroll
        for (int j = 0; j < NL; j++) Wv[c][j] = wp[j];
    }

    int gbase = bx * 8;                  // 8 row-groups of 4 rows = rows [32bx,32bx+32)
    float ph[4][3];
#pragma unroll
    for (int r = 0; r < 4; r++) {
        const float* hp = hidden + (size_t)(4 * gbase + r) * NH + kbase;
        ph[r][0] = hp[0]; ph[r][1] = hp[64]; ph[r][2] = hp[128];
    }
#pragma unroll
    for (int it = 0; it < 8; ++it) {
        float ch[4][3];
#pragma unroll
        for (int r = 0; r < 4; r++) {
            ch[r][0] = ph[r][0]; ch[r][1] = ph[r][1]; ch[r][2] = ph[r][2];
        }
        if (it < 7) {
            int gn = gbase + it + 1;
#pragma unroll
            for (int r = 0; r < 4; r++) {
                const float* hp = hidden + (size_t)(4 * gn + r) * NH + kbase;
                ph[r][0] = hp[0]; ph[r][1] = hp[64]; ph[r][2] = hp[128];
            }
        }
        int grow = gbase + it;
#pragma unroll
        for (int r = 0; r < 4; r++) {
            float acc[NL];
#pragma unroll
            for (int j = 0; j < NL; j++) {
                acc[j] = fmaf(ch[r][0], Wv[0][j], fmaf(ch[r][1], Wv[1][j], ch[r][2] * Wv[2][j]));
            }
#pragma unroll
            for (int j = 0; j < NL; j++) acc[j] = wave_sum_to63(acc[j]);
            if (lane == 63) {
#pragma unroll
                for (int j = 0; j < NL; j++) s_part[w][r][j] = acc[j];
            }
        }
        __syncthreads();
        if (tid < 36) {
            int r = tid / NL, j = tid % NL;
            float v = (s_part[0][r][j] + s_part[1][r][j]) +
                      (s_part[2][r][j] + s_part[3][r][j]) + bias[j];
            em[(size_t)(4 * grow + r) * NL + j] = v;
        }
        __syncthreads();
    }
}

// ---------------- Kernel B: DP + finalize (quad_perm chains) ----------------
// Chains use 4 lanes per batch (16 active lanes = 4 batches/wave). Each lane owns
// 2-3 columns: g0={0,1,2}, g1={3,4}, g2={5,6}, g3={7,8} (2-col lanes duplicate
// their last column; duplicates are benign). Per step: compute owned columns from
// the full 9-state register set, then rebuild all 9 states in every lane with
// NINE quad_perm DPP moves (~4cy VALU) instead of nine ds_swizzle LDS round trips
// (~120cy on the serial critical path). All fp op trees verbatim R2 -> bit-exact.
__global__ __launch_bounds__(256) void k_dp(const float* __restrict__ em,
                                            const int* __restrict__ label,
                                            const int* __restrict__ mask,
                                            const float* __restrict__ startT,
                                            const float* __restrict__ endT,
                                            const float* __restrict__ trans,
                                            float* __restrict__ out) {
    __shared__ float s_T[NL * NL];
    __shared__ int s_mki[4][NS];
    __shared__ float s_v[4 * VST];
    __shared__ unsigned char s_bp[4 * BPST];
    __shared__ unsigned char s_path[4 * NS];

    int bx = blockIdx.x;
    int tid = threadIdx.x;
    int lane = tid & 63;
    bool isfwd = bx < 16;
    int b0 = (isfwd ? bx : (bx - 16)) * 4;

    if (tid < NL * NL) s_T[tid] = trans[tid];
    if (isfwd) {
        for (int q = tid; q < 4 * NS / 4; q += 256)
            ((int4*)s_mki)[q] = ((const int4*)(mask + b0 * NS))[q];
    }
    __syncthreads();

// rebuild full 9-state set from per-lane owned values (within each 4-lane quad)
#define EXCH(D0,D1,D2,D3,D4,D5,D6,D7,D8, XA_,XB_,XC_) do { \
    D0 = qperm<0x00>(XA_); D1 = qperm<0x00>(XB_); D2 = qperm<0x00>(XC_); \
    D3 = qperm<0x55>(XA_); D4 = qperm<0x55>(XB_); \
    D5 = qperm<0xAA>(XA_); D6 = qperm<0xAA>(XB_); \
    D7 = qperm<0xFF>(XA_); D8 = qperm<0xFF>(XB_); \
} while (0)

    if (isfwd) {
        if (tid < 64) {
            if (lane < 16) {
                // ---- forward chains: 4 batches, 4 lanes each ----
                int bb = lane >> 2;
                int g = lane & 3;
                int cA = (g == 0) ? 0 : (g == 1) ? 3 : (g == 2) ? 5 : 7;
                int cB = (g == 0) ? 1 : (g == 1) ? 4 : (g == 2) ? 6 : 8;
                int cC = (g == 0) ? 2 : cB;
                const float* gpb = em + (size_t)(b0 + bb) * (NS * NL);
                float McA[NL], McB[NL], McC[NL];
#pragma unroll
                for (int i = 0; i < NL; i++) {
                    McA[i] = __expf(s_T[i * NL + cA]);
                    McB[i] = __expf(s_T[i * NL + cB]);
                    McC[i] = __expf(s_T[i * NL + cC]);
                }
                float xA = __expf(startT[cA] + gpb[cA]);
                float xB = __expf(startT[cB] + gpb[cB]);
                float xC = __expf(startT[cC] + gpb[cC]);
                float a0, a1, a2, a3, a4, a5, a6, a7, a8;
                EXCH(a0,a1,a2,a3,a4,a5,a6,a7,a8, xA, xB, xC);
                int eacc = 0;

#define FSTEP(EA_, EB_, EC_, KC_) do { \
    float pA0=a0*McA[0],pA1=a1*McA[1],pA2=a2*McA[2],pA3=a3*McA[3],pA4=a4*McA[4], \
          pA5=a5*McA[5],pA6=a6*McA[6],pA7=a7*McA[7],pA8=a8*McA[8]; \
    float pB0=a0*McB[0],pB1=a1*McB[1],pB2=a2*McB[2],pB3=a3*McB[3],pB4=a4*McB[4], \
          pB5=a5*McB[5],pB6=a6*McB[6],pB7=a7*McB[7],pB8=a8*McB[8]; \
    float pC0=a0*McC[0],pC1=a1*McC[1],pC2=a2*McC[2],pC3=a3*McC[3],pC4=a4*McC[4], \
          pC5=a5*McC[5],pC6=a6*McC[6],pC7=a7*McC[7],pC8=a8*McC[8]; \
    float sA=(((pA0+pA1)+(pA2+pA3))+((pA4+pA5)+(pA6+pA7)))+pA8; \
    float sB=(((pB0+pB1)+(pB2+pB3))+((pB4+pB5)+(pB6+pB7)))+pB8; \
    float sC=(((pC0+pC1)+(pC2+pC3))+((pC4+pC5)+(pC6+pC7)))+pC8; \
    float anA=(EA_)*sA, anB=(EB_)*sB, anC=(EC_)*sC; \
    bool km = (KC_) > 0; \
    xA = km ? anA : xA; xB = km ? anB : xB; xC = km ? anC : xC; \
    EXCH(a0,a1,a2,a3,a4,a5,a6,a7,a8, xA, xB, xC); \
} while (0)

#define FREN() do { \
    float cc=(((a0+a1)+(a2+a3))+((a4+a5)+(a6+a7)))+a8; \
    int ex=((__float_as_int(cc)>>23)&255)-127; \
    xA=ldexpf(xA,-ex); xB=ldexpf(xB,-ex); xC=ldexpf(xC,-ex); \
    a0=ldexpf(a0,-ex); a1=ldexpf(a1,-ex); a2=ldexpf(a2,-ex); \
    a3=ldexpf(a3,-ex); a4=ldexpf(a4,-ex); a5=ldexpf(a5,-ex); \
    a6=ldexpf(a6,-ex); a7=ldexpf(a7,-ex); a8=ldexpf(a8,-ex); \
    eacc += ex; \
} while (0)

                float eA8[8], eB8[8], eC8[8]; int k8[8];
#pragma unroll
                for (int p = 0; p < 8; p++) {
                    int t = 1 + p;
                    eA8[p] = __expf(gpb[t * NL + cA]);
                    eB8[p] = __expf(gpb[t * NL + cB]);
                    eC8[p] = __expf(gpb[t * NL + cC]);
                    k8[p] = s_mki[bb][t];
                }
                for (int t0 = 1; t0 <= NS - 15; t0 += 8) {
#pragma unroll
                    for (int p = 0; p < 8; p++) {
                        int t = t0 + p;
                        float eA = eA8[p], eB = eB8[p], eC = eC8[p]; int kc = k8[p];
                        int tn = t + 8; tn = tn > NS - 1 ? NS - 1 : tn;
                        eA8[p] = __expf(gpb[tn * NL + cA]);
                        eB8[p] = __expf(gpb[tn * NL + cB]);
                        eC8[p] = __expf(gpb[tn * NL + cC]);
                        k8[p] = s_mki[bb][tn];
                        FSTEP(eA, eB, eC, kc);
                        if (p == 7) FREN();
                    }
                }
#pragma unroll
                for (int p = 0; p < 7; p++) FSTEP(eA8[p], eB8[p], eC8[p], k8[p]);
#undef FSTEP
#undef FREN
                float z0 = a0 * __expf(endT[0]), z1 = a1 * __expf(endT[1]);
                float z2 = a2 * __expf(endT[2]), z3 = a3 * __expf(endT[3]);
                float z4 = a4 * __expf(endT[4]), z5 = a5 * __expf(endT[5]);
                float z6 = a6 * __expf(endT[6]), z7 = a7 * __expf(endT[7]);
                float z8 = a8 * __expf(endT[8]);
                float c = (((z0 + z1) + (z2 + z3)) + ((z4 + z5) + (z6 + z7))) + z8;
                if (g == 0) {
                    float lz = (float)eacc * 0.6931471805599453f + __logf(c);
                    atomicAdd(out, lz * (1.0f / (float)NB));
                }
            }
        } else if (tid < 128) {
            // ---- numerator (unchanged R2) ----
            int g = lane >> 4;
            int ll = lane & 15;
            int b = b0 + g;
            const int* lb = label + b * NS;
            const float* ge = em + (size_t)b * NS * NL;
            int h = 0, sl = 0;
            for (int cch = 0; cch < 4; cch++) {
                int la8[8]; int mk8[8];
#pragma unroll
                for (int r = 0; r < 8; r++) {
                    int t = ll * 32 + cch * 8 + r;
                    la8[r] = lb[t];
                    int m = s_mki[g][t];
                    if (t == 0) m = 1;
                    mk8[r] = m;
                }
#pragma unroll
                for (int r = 0; r < 8; r++) if (mk8[r] > 0) { h = 1; sl = la8[r]; }
            }
#pragma unroll
            for (int d = 1; d < 16; d <<= 1) {
                int ho = __shfl_up(h, d, 16);
                int so = __shfl_up(sl, d, 16);
                if (!h) { h = ho; sl = so; }
            }
            int lg = __shfl(sl, 15, 16);
            int incoming = __shfl_up(sl, 1, 16);
            int labz = lb[0];
            int prevr = (ll == 0) ? labz : incoming;
            float sc = 0.f;
            for (int cch = 0; cch < 4; cch++) {
                int la8[8]; int mk8[8]; float ev8[8];
#pragma unroll
                for (int r = 0; r < 8; r++) {
                    int t = ll * 32 + cch * 8 + r;
                    la8[r] = lb[t];
                    int m = s_mki[g][t];
                    if (t == 0) m = 1;
                    mk8[r] = m;
                }
#pragma unroll
                for (int r = 0; r < 8; r++) {
                    int t = ll * 32 + cch * 8 + r;
                    ev8[r] = ge[t * NL + la8[r]];
                }
#pragma unroll
                for (int r = 0; r < 8; r++) {
                    int t = ll * 32 + cch * 8 + r;
                    if (t > 0) {
                        float s = s_T[prevr * NL + la8[r]] + ev8[r];
                        sc += s * (float)mk8[r];
                    }
                    if (mk8[r] > 0) prevr = la8[r];
                }
            }
            if (ll == 0) sc += startT[labz] + ge[labz] + endT[lg];
#pragma unroll
            for (int d = 1; d < 16; d <<= 1) sc += __shfl_xor(sc, d, 16);
            if (ll == 0) atomicAdd(out, -sc * (1.0f / (float)NB));
        }
    } else {
        // ---- Viterbi chains: 4 batches, 4 lanes each (bit-exact trees) ----
        if (tid < 64 && lane < 16) {
            int bb = lane >> 2;
            int g = lane & 3;
            int cA = (g == 0) ? 0 : (g == 1) ? 3 : (g == 2) ? 5 : 7;
            int cB = (g == 0) ? 1 : (g == 1) ? 4 : (g == 2) ? 6 : 8;
            int cC = (g == 0) ? 2 : cB;
            const float* gpb = em + (size_t)(b0 + bb) * (NS * NL);
            float TcA[NL], TcB[NL], TcC[NL];
#pragma unroll
            for (int i = 0; i < NL; i++) {
                TcA[i] = s_T[i * NL + cA];
                TcB[i] = s_T[i * NL + cB];
                TcC[i] = s_T[i * NL + cC];
            }
            int svb = bb * VST;
            float yA = startT[cA] + gpb[cA];
            float yB = startT[cB] + gpb[cB];
            float yC = startT[cC] + gpb[cC];
            s_v[svb + cA] = yA; s_v[svb + cB] = yB; s_v[svb + cC] = yC;  // t = 0
            float v0, v1, v2, v3, v4, v5, v6, v7, v8;
            EXCH(v0,v1,v2,v3,v4,v5,v6,v7,v8, yA, yB, yC);

#define VSTEP(EA_, EB_, EC_, T_) do { \
    float mA0=v0+TcA[0],mA1=v1+TcA[1],mA2=v2+TcA[2],mA3=v3+TcA[3],mA4=v4+TcA[4], \
          mA5=v5+TcA[5],mA6=v6+TcA[6],mA7=v7+TcA[7],mA8=v8+TcA[8]; \
    float mB0=v0+TcB[0],mB1=v1+TcB[1],mB2=v2+TcB[2],mB3=v3+TcB[3],mB4=v4+TcB[4], \
          mB5=v5+TcB[5],mB6=v6+TcB[6],mB7=v7+TcB[7],mB8=v8+TcB[8]; \
    float mC0=v0+TcC[0],mC1=v1+TcC[1],mC2=v2+TcC[2],mC3=v3+TcC[3],mC4=v4+TcC[4], \
          mC5=v5+TcC[5],mC6=v6+TcC[6],mC7=v7+TcC[7],mC8=v8+TcC[8]; \
    float MA=fmaxf(fmaxf(fmaxf(fmaxf(mA0,mA1),mA2),fmaxf(fmaxf(mA3,mA4),mA5)),fmaxf(fmaxf(mA6,mA7),mA8)); \
    float MB=fmaxf(fmaxf(fmaxf(fmaxf(mB0,mB1),mB2),fmaxf(fmaxf(mB3,mB4),mB5)),fmaxf(fmaxf(mB6,mB7),mB8)); \
    float MC=fmaxf(fmaxf(fmaxf(fmaxf(mC0,mC1),mC2),fmaxf(fmaxf(mC3,mC4),mC5)),fmaxf(fmaxf(mC6,mC7),mC8)); \
    yA = MA + (EA_); yB = MB + (EB_); yC = MC + (EC_); \
    s_v[svb + (T_) * NL + cA] = yA; \
    s_v[svb + (T_) * NL + cB] = yB; \
    s_v[svb + (T_) * NL + cC] = yC; \
    EXCH(v0,v1,v2,v3,v4,v5,v6,v7,v8, yA, yB, yC); \
} while (0)

            float eA8[8], eB8[8], eC8[8];
#pragma unroll
            for (int p = 0; p < 8; p++) {
                int t = 1 + p;
                eA8[p] = gpb[t * NL + cA];
                eB8[p] = gpb[t * NL + cB];
                eC8[p] = gpb[t * NL + cC];
            }
            for (int t0 = 1; t0 <= NS - 15; t0 += 8) {
#pragma unroll
                for (int p = 0; p < 8; p++) {
                    int t = t0 + p;
                    float eA = eA8[p], eB = eB8[p], eC = eC8[p];
                    int tn = t + 8; tn = tn > NS - 1 ? NS - 1 : tn;
                    eA8[p] = gpb[tn * NL + cA];
                    eB8[p] = gpb[tn * NL + cB];
                    eC8[p] = gpb[tn * NL + cC];
                    VSTEP(eA, eB, eC, t);
                }
            }
#pragma unroll
            for (int p = 0; p < 7; p++) VSTEP(eA8[p], eB8[p], eC8[p], 505 + p);
#undef VSTEP
        }
        __syncthreads();
        // ---- phase 2: backpointers (unchanged R2) ----
        for (int it = 0; it < 8; it++) {
            int item = tid + it * 256;
            int bb = item >> 9;
            int t = item & (NS - 1);
            if (t > 0) {
                const float* vpp = s_v + bb * VST + (t - 1) * NL;
                const float* ge = em + (size_t)(b0 + bb) * (NS * NL) + t * NL;
                float vp[NL], emt[NL];
#pragma unroll
                for (int i = 0; i < NL; i++) vp[i] = vpp[i];
#pragma unroll
                for (int j = 0; j < NL; j++) emt[j] = ge[j];
#pragma unroll
                for (int j = 0; j < NL; j++) {
                    float e = emt[j];
                    float val[NL];
#pragma unroll
                    for (int i = 0; i < NL; i++) val[i] = (vp[i] + s_T[i * NL + j]) + e;
                    bool c01 = val[0] >= val[1]; float m01 = c01 ? val[0] : val[1]; int i01 = c01 ? 0 : 1;
                    bool c23 = val[2] >= val[3]; float m23 = c23 ? val[2] : val[3]; int i23 = c23 ? 2 : 3;
                    bool c45 = val[4] >= val[5]; float m45 = c45 ? val[4] : val[5]; int i45 = c45 ? 4 : 5;
                    bool c67 = val[6] >= val[7]; float m67 = c67 ? val[6] : val[7]; int i67 = c67 ? 6 : 7;
                    bool ca = m01 >= m23; float ma = ca ? m01 : m23; int ia = ca ? i01 : i23;
                    bool cb = m45 >= m67; float mb = cb ? m45 : m67; int ib = cb ? i45 : i67;
                    bool cc = ma >= mb;  float mc = cc ? ma : mb;  int ic = cc ? ia : ib;
                    bool cd = mc >= val[8]; int bi = cd ? ic : 8;
                    s_bp[bb * BPST + t * NL + j] = (unsigned char)bi;
                }
            }
        }
        __syncthreads();
        // ---- phase 3: backtrack (unchanged R2) ----
        {
            int w = tid >> 6;
            const float* sv = s_v + w * VST;
            const unsigned char* bpp = s_bp + w * BPST;
            unsigned char* pth = s_path + w * NS;
            float bb2 = sv[(NS - 1) * NL + 0] + endT[0]; int lt = 0;
#pragma unroll
            for (int jj = 1; jj < NL; jj++) {
                float fj = sv[(NS - 1) * NL + jj] + endT[jj];
                if (fj > bb2) { bb2 = fj; lt = jj; }
            }
            unsigned long long G[8];
#pragma unroll
            for (int r = 0; r < 8; r++) {
                int t0 = (lane * 8 + r) * NL;
                unsigned long long g = 0;
                if (lane == 0 && r == 0) {
                    g = 0x876543210ULL;
                } else {
#pragma unroll
                    for (int x = 0; x < NL; x++) g |= (unsigned long long)bpp[t0 + x] << (4 * x);
                }
                G[r] = g;
            }
            unsigned long long A = 0x876543210ULL;
#pragma unroll
            for (int r = 7; r >= 0; r--) {
                unsigned long long An = 0;
#pragma unroll
                for (int x = 0; x < NL; x++) {
                    int ax = (int)((A >> (4 * x)) & 15ULL);
                    int gvv = (int)((G[r] >> (4 * ax)) & 15ULL);
                    An |= (unsigned long long)gvv << (4 * x);
                }
                A = An;
            }
            int e = 0; int cur = lt;
            for (int llv = 63; llv >= 0; --llv) {
                if (lane == llv) e = cur;
                unsigned long long Al = readlane_u64(A, llv);
                cur = (int)((Al >> (4 * cur)) & 15ULL);
            }
            unsigned long long pw = 0; int c2 = e;
#pragma unroll
            for (int r = 7; r >= 0; r--) {
                pw |= (unsigned long long)c2 << (8 * r);
                c2 = (int)((G[r] >> (4 * c2)) & 15ULL);
            }
            *(unsigned long long*)(pth + lane * 8) = pw;
        }
        __syncthreads();
        // ---- finalize (unchanged R2) ----
        float cnt = 0.f;
#pragma unroll
        for (int q = 0; q < 8; q++) {
            int item = tid + q * 256;
            int bb = item >> 9;
            int t = item & (NS - 1);
            int b = b0 + bb;
            int idx = b * NS + t;
            int lab = label[idx];
            int p = (int)s_path[bb * NS + t];
            int pred = (lab > 0) ? p : 0;
            out[2 + idx] = (float)pred;
            out[2 + NROWS + idx] = (float)lab;
            cnt += (pred == lab) ? 1.f : 0.f;
        }
#pragma unroll
        for (int d = 1; d < 64; d <<= 1) cnt += __shfl_xor(cnt, d);
        if ((tid & 63) == 0) atomicAdd(out + 1, cnt);
    }
#undef EXCH
}

extern "C" void kernel_launch(void* const* d_in, const int* in_sizes, int n_in,
                              void* d_out, int out_size, void* d_ws, size_t ws_size,
                              hipStream_t stream) {
    const float* hidden = (const float*)d_in[0];
    const int*   label  = (const int*)d_in[1];
    const int*   mask   = (const int*)d_in[2];
    const float* W      = (const float*)d_in[3];
    const float* bias   = (const float*)d_in[4];
    const float* startT = (const float*)d_in[5];
    const float* endT   = (const float*)d_in[6];
    const float* trans  = (const float*)d_in[7];
    float* out = (float*)d_out;

    float* em = (float*)d_ws;   // EMN floats

    k_gemm<<<1024, 256, 0, stream>>>(hidden, W, bias, em, out);
    k_dp<<<32, 256, 0, stream>>>(em, label, mask, startT, endT, trans, out);
}

// Round 8
// 214.369 us; speedup vs baseline: 2.6193x; 1.2748x over previous
//
#include <hip/hip_runtime.h>
#include <hip/hip_bf16.h>

// Problem constants: B=64, S=512, H=768, L=9
#define NB 64
#define NS 512
#define NH 768
#define NL 9
#define NROWS (NB*NS)          // 32768
#define EMN (NROWS*NL)         // 294912

// per-batch LDS strides (padded off %32==0)
#define VST  4617              // floats per batch for s_v
#define BPST 4616              // bytes  per batch for s_bp

__device__ __forceinline__ unsigned long long readlane_u64(unsigned long long v, int l) {
    unsigned int lo = (unsigned int)__builtin_amdgcn_readlane((int)(unsigned int)(v & 0xffffffffULL), l);
    unsigned int hi = (unsigned int)__builtin_amdgcn_readlane((int)(unsigned int)(v >> 32), l);
    return ((unsigned long long)hi << 32) | (unsigned long long)lo;
}
template <int CTRL>
__device__ __forceinline__ float dpp_add(float x) {
    int t = __builtin_amdgcn_update_dpp(0, __float_as_int(x), CTRL, 0xf, 0xf, false);
    return x + __int_as_float(t);
}
__device__ __forceinline__ float wave_sum_to63(float x) {
    x = dpp_add<0x111>(x);  // row_shr:1
    x = dpp_add<0x112>(x);  // row_shr:2
    x = dpp_add<0x114>(x);  // row_shr:4
    x = dpp_add<0x118>(x);  // row_shr:8
    x = dpp_add<0x142>(x);  // row_bcast:15
    x = dpp_add<0x143>(x);  // row_bcast:31 -> lane63 = wave sum
    return x;
}
// ds_swizzle row-broadcast: lane receives value of lane I of its 16-lane row.
template <int I>
__device__ __forceinline__ float rowbc(float x) {
    return __int_as_float(__builtin_amdgcn_ds_swizzle(__float_as_int(x), (I << 5) | 0x10));
}

// ---------------- Kernel A: emissions GEMM (persistent W, grid-stride) ----------
// R7-proven variant (45.1us vs 48.8 for the 8192-block version; bit-identical em).
// 1024 blocks x 256 thr co-resident. W preload once per block; 8 row-groups of 4
// rows with next-group hidden prefetched into registers. FMA + wave_sum tree +
// 4-wave combine verbatim from the original proven kernel.
__global__ __launch_bounds__(256) void k_gemm(const float* __restrict__ hidden,
                                              const float* __restrict__ W,
                                              const float* __restrict__ bias,
                                              float* __restrict__ em,
                                              float* __restrict__ out) {
    __shared__ float s_part[4][4][NL];
    int tid = threadIdx.x;
    int lane = tid & 63;
    int w = tid >> 6;
    int bx = blockIdx.x;
    if (bx == 0 && tid == 0) { out[0] = 0.f; out[1] = 0.f; }

    int kbase = 192 * w + lane;
    float Wv[3][NL];
#pragma unroll
    for (int c = 0; c < 3; c++) {
        const float* wp = W + (size_t)(kbase + 64 * c) * NL;
#pragma unroll
        for (int j = 0; j < NL; j++) Wv[c][j] = wp[j];
    }

    int gbase = bx * 8;                  // rows [32bx, 32bx+32)
    float ph[4][3];
#pragma unroll
    for (int r = 0; r < 4; r++) {
        const float* hp = hidden + (size_t)(4 * gbase + r) * NH + kbase;
        ph[r][0] = hp[0]; ph[r][1] = hp[64]; ph[r][2] = hp[128];
    }
#pragma unroll
    for (int it = 0; it < 8; ++it) {
        float ch[4][3];
#pragma unroll
        for (int r = 0; r < 4; r++) {
            ch[r][0] = ph[r][0]; ch[r][1] = ph[r][1]; ch[r][2] = ph[r][2];
        }
        if (it < 7) {
            int gn = gbase + it + 1;
#pragma unroll
            for (int r = 0; r < 4; r++) {
                const float* hp = hidden + (size_t)(4 * gn + r) * NH + kbase;
                ph[r][0] = hp[0]; ph[r][1] = hp[64]; ph[r][2] = hp[128];
            }
        }
        int grow = gbase + it;
#pragma unroll
        for (int r = 0; r < 4; r++) {
            float acc[NL];
#pragma unroll
            for (int j = 0; j < NL; j++) {
                acc[j] = fmaf(ch[r][0], Wv[0][j], fmaf(ch[r][1], Wv[1][j], ch[r][2] * Wv[2][j]));
            }
#pragma unroll
            for (int j = 0; j < NL; j++) acc[j] = wave_sum_to63(acc[j]);
            if (lane == 63) {
#pragma unroll
                for (int j = 0; j < NL; j++) s_part[w][r][j] = acc[j];
            }
        }
        __syncthreads();
        if (tid < 36) {
            int r = tid / NL, j = tid % NL;
            float v = (s_part[0][r][j] + s_part[1][r][j]) +
                      (s_part[2][r][j] + s_part[3][r][j]) + bias[j];
            em[(size_t)(4 * grow + r) * NL + j] = v;
        }
        __syncthreads();
    }
}

// ---------------- Kernel B: DP + finalize (R2-proven rowbc chains) ----------------
// One change vs R2: the forward renorm's dedicated 9-swizzle round trip (FREN) is
// FUSED into the following step. The next step's swizzles already deliver all 9
// unscaled a_i; the same sum tree gives the same ex, products use unscaled a_i and
// the exact-pow2 scale is applied after the update. Pow2 scaling commutes bitwise
// with mul/add (no denormals/overflow here: states stay within ~e^5 of each other)
// -> logZ bit-identical, 63 LDS round trips removed from the serial critical path.
__global__ __launch_bounds__(256) void k_dp(const float* __restrict__ em,
                                            const int* __restrict__ label,
                                            const int* __restrict__ mask,
                                            const float* __restrict__ startT,
                                            const float* __restrict__ endT,
                                            const float* __restrict__ trans,
                                            float* __restrict__ out) {
    __shared__ float s_T[NL * NL];
    __shared__ int s_mki[4][NS];
    __shared__ float s_v[4 * VST];
    __shared__ unsigned char s_bp[4 * BPST];
    __shared__ unsigned char s_path[4 * NS];

    int bx = blockIdx.x;
    int tid = threadIdx.x;
    int lane = tid & 63;
    bool isfwd = bx < 16;
    int b0 = (isfwd ? bx : (bx - 16)) * 4;

    if (tid < NL * NL) s_T[tid] = trans[tid];
    if (isfwd) {
        for (int q = tid; q < 4 * NS / 4; q += 256)
            ((int4*)s_mki)[q] = ((const int4*)(mask + b0 * NS))[q];
    }
    __syncthreads();

    if (isfwd) {
        if (tid < 64) {
            // ---- forward algorithm, 4 batches (one per 16-lane row) ----
            int bb = lane >> 4;
            int jcol = lane & 15;
            int jcol9 = jcol < NL ? jcol : NL - 1;
            const float* gp = em + (size_t)(b0 + bb) * (NS * NL) + jcol9;
            float Mc0 = __expf(s_T[0 * NL + jcol9]);
            float Mc1 = __expf(s_T[1 * NL + jcol9]);
            float Mc2 = __expf(s_T[2 * NL + jcol9]);
            float Mc3 = __expf(s_T[3 * NL + jcol9]);
            float Mc4 = __expf(s_T[4 * NL + jcol9]);
            float Mc5 = __expf(s_T[5 * NL + jcol9]);
            float Mc6 = __expf(s_T[6 * NL + jcol9]);
            float Mc7 = __expf(s_T[7 * NL + jcol9]);
            float Mc8 = __expf(s_T[8 * NL + jcol9]);
            float a = __expf(startT[jcol9] + gp[0]);
            int eacc = 0;

#define FBODY(EC_, KC_) do { \
    float _w0=rowbc<0>(a),_w1=rowbc<1>(a),_w2=rowbc<2>(a),_w3=rowbc<3>(a),_w4=rowbc<4>(a), \
          _w5=rowbc<5>(a),_w6=rowbc<6>(a),_w7=rowbc<7>(a),_w8=rowbc<8>(a); \
    float _p0=_w0*Mc0,_p1=_w1*Mc1,_p2=_w2*Mc2,_p3=_w3*Mc3,_p4=_w4*Mc4, \
          _p5=_w5*Mc5,_p6=_w6*Mc6,_p7=_w7*Mc7,_p8=_w8*Mc8; \
    float _s=(((_p0+_p1)+(_p2+_p3))+((_p4+_p5)+(_p6+_p7)))+_p8; \
    float _an=(EC_)*_s; \
    a = ((KC_) > 0) ? _an : a; \
} while (0)

// FBODY with the pending renorm (from the previous step's end) fused in.
// _cc tree over the swizzled UNSCALED a_i is identical to R2's FREN tree ->
// identical ex; exact-pow2 scale applied after the masked update.
#define FBODY_REN(EC_, KC_) do { \
    float _w0=rowbc<0>(a),_w1=rowbc<1>(a),_w2=rowbc<2>(a),_w3=rowbc<3>(a),_w4=rowbc<4>(a), \
          _w5=rowbc<5>(a),_w6=rowbc<6>(a),_w7=rowbc<7>(a),_w8=rowbc<8>(a); \
    float _cc=(((_w0+_w1)+(_w2+_w3))+((_w4+_w5)+(_w6+_w7)))+_w8; \
    int _ex=((__float_as_int(_cc)>>23)&255)-127; \
    float _p0=_w0*Mc0,_p1=_w1*Mc1,_p2=_w2*Mc2,_p3=_w3*Mc3,_p4=_w4*Mc4, \
          _p5=_w5*Mc5,_p6=_w6*Mc6,_p7=_w7*Mc7,_p8=_w8*Mc8; \
    float _s=(((_p0+_p1)+(_p2+_p3))+((_p4+_p5)+(_p6+_p7)))+_p8; \
    float _an=(EC_)*_s; \
    a = ((KC_) > 0) ? _an : a; \
    a = ldexpf(a, -_ex); \
    eacc += _ex; \
} while (0)

            float e8[8]; int k8[8];
#pragma unroll
            for (int p = 0; p < 8; p++) {
                e8[p] = __expf(gp[(1 + p) * NL]);
                k8[p] = s_mki[bb][1 + p];
            }
            for (int t0 = 1; t0 <= NS - 15; t0 += 8) {   // t0 = 1,9,...,497
#pragma unroll
                for (int p = 0; p < 8; p++) {
                    int t = t0 + p;
                    float ec = e8[p]; int kc = k8[p];
                    int tn = t + 8; tn = tn > NS - 1 ? NS - 1 : tn;
                    e8[p] = __expf(gp[tn * NL]);
                    k8[p] = s_mki[bb][tn];
                    if (p == 0 && t0 > 1) {
                        FBODY_REN(ec, kc);               // applies renorm from t0-1
                    } else {
                        FBODY(ec, kc);
                    }
                }
            }
            // tail t = 505..511; renorm from t=504 fused into t=505
            FBODY_REN(e8[0], k8[0]);
#pragma unroll
            for (int p = 1; p < 7; p++) FBODY(e8[p], k8[p]);
#undef FBODY
#undef FBODY_REN
            float z = a * __expf(endT[jcol9]);
            float c0 = rowbc<0>(z), c1 = rowbc<1>(z), c2 = rowbc<2>(z);
            float c3 = rowbc<3>(z), c4 = rowbc<4>(z), c5 = rowbc<5>(z);
            float c6 = rowbc<6>(z), c7 = rowbc<7>(z), c8 = rowbc<8>(z);
            float c = (((c0 + c1) + (c2 + c3)) + ((c4 + c5) + (c6 + c7))) + c8;
            if (jcol == 0) {
                float lz = (float)eacc * 0.6931471805599453f + __logf(c);
                atomicAdd(out, lz * (1.0f / (float)NB));
            }
        } else if (tid < 128) {
            // ---- numerator (gold path score), one 16-lane group per batch ----
            int g = lane >> 4;
            int ll = lane & 15;
            int b = b0 + g;
            const int* lb = label + b * NS;
            const float* ge = em + (size_t)b * NS * NL;
            int h = 0, sl = 0;
            for (int cch = 0; cch < 4; cch++) {
                int la8[8]; int mk8[8];
#pragma unroll
                for (int r = 0; r < 8; r++) {
                    int t = ll * 32 + cch * 8 + r;
                    la8[r] = lb[t];
                    int m = s_mki[g][t];
                    if (t == 0) m = 1;
                    mk8[r] = m;
                }
#pragma unroll
                for (int r = 0; r < 8; r++) if (mk8[r] > 0) { h = 1; sl = la8[r]; }
            }
#pragma unroll
            for (int d = 1; d < 16; d <<= 1) {
                int ho = __shfl_up(h, d, 16);
                int so = __shfl_up(sl, d, 16);
                if (!h) { h = ho; sl = so; }
            }
            int lg = __shfl(sl, 15, 16);
            int incoming = __shfl_up(sl, 1, 16);
            int labz = lb[0];
            int prevr = (ll == 0) ? labz : incoming;
            float sc = 0.f;
            for (int cch = 0; cch < 4; cch++) {
                int la8[8]; int mk8[8]; float ev8[8];
#pragma unroll
                for (int r = 0; r < 8; r++) {
                    int t = ll * 32 + cch * 8 + r;
                    la8[r] = lb[t];
                    int m = s_mki[g][t];
                    if (t == 0) m = 1;
                    mk8[r] = m;
                }
#pragma unroll
                for (int r = 0; r < 8; r++) {
                    int t = ll * 32 + cch * 8 + r;
                    ev8[r] = ge[t * NL + la8[r]];
                }
#pragma unroll
                for (int r = 0; r < 8; r++) {
                    int t = ll * 32 + cch * 8 + r;
                    if (t > 0) {
                        float s = s_T[prevr * NL + la8[r]] + ev8[r];
                        sc += s * (float)mk8[r];
                    }
                    if (mk8[r] > 0) prevr = la8[r];
                }
            }
            if (ll == 0) sc += startT[labz] + ge[labz] + endT[lg];
#pragma unroll
            for (int d = 1; d < 16; d <<= 1) sc += __shfl_xor(sc, d, 16);
            if (ll == 0) atomicAdd(out, -sc * (1.0f / (float)NB));
        }
    } else {
        // ---- Viterbi phase 1: 4 value chains (one per 16-lane row), bit-exact ----
        if (tid < 64) {
            int bb = lane >> 4;
            int jcol = lane & 15;
            int jcol9 = jcol < NL ? jcol : NL - 1;
            const float* gv = em + (size_t)(b0 + bb) * (NS * NL) + jcol9;
            float Tc0 = s_T[0 * NL + jcol9];
            float Tc1 = s_T[1 * NL + jcol9];
            float Tc2 = s_T[2 * NL + jcol9];
            float Tc3 = s_T[3 * NL + jcol9];
            float Tc4 = s_T[4 * NL + jcol9];
            float Tc5 = s_T[5 * NL + jcol9];
            float Tc6 = s_T[6 * NL + jcol9];
            float Tc7 = s_T[7 * NL + jcol9];
            float Tc8 = s_T[8 * NL + jcol9];
            float v = startT[jcol9] + gv[0];
            int svbase = bb * VST + jcol;
            s_v[svbase] = v;
#define VBODY(EC_, T_) do { \
    float _w0=rowbc<0>(v),_w1=rowbc<1>(v),_w2=rowbc<2>(v),_w3=rowbc<3>(v),_w4=rowbc<4>(v), \
          _w5=rowbc<5>(v),_w6=rowbc<6>(v),_w7=rowbc<7>(v),_w8=rowbc<8>(v); \
    float _m0=_w0+Tc0,_m1=_w1+Tc1,_m2=_w2+Tc2,_m3=_w3+Tc3,_m4=_w4+Tc4, \
          _m5=_w5+Tc5,_m6=_w6+Tc6,_m7=_w7+Tc7,_m8=_w8+Tc8; \
    float _Ma=fmaxf(fmaxf(_m0,_m1),_m2); \
    float _Mb=fmaxf(fmaxf(_m3,_m4),_m5); \
    float _Mc=fmaxf(fmaxf(_m6,_m7),_m8); \
    v = fmaxf(fmaxf(_Ma,_Mb),_Mc) + (EC_); \
    s_v[svbase + (T_) * NL] = v; \
} while (0)
            float e8[8];
#pragma unroll
            for (int p = 0; p < 8; p++) e8[p] = gv[(1 + p) * NL];
            for (int t0 = 1; t0 <= NS - 15; t0 += 8) {
#pragma unroll
                for (int p = 0; p < 8; p++) {
                    int t = t0 + p;
                    float ec = e8[p];
                    int tn = t + 8; tn = tn > NS - 1 ? NS - 1 : tn;
                    e8[p] = gv[tn * NL];
                    VBODY(ec, t);
                }
            }
#pragma unroll
            for (int p = 0; p < 7; p++) VBODY(e8[p], 505 + p);
#undef VBODY
        }
        __syncthreads();
        // ---- phase 2: backpointers, parallel over (batch, t); exact ref op order ----
        for (int it = 0; it < 8; it++) {
            int item = tid + it * 256;
            int bb = item >> 9;
            int t = item & (NS - 1);
            if (t > 0) {
                const float* vpp = s_v + bb * VST + (t - 1) * NL;
                const float* ge = em + (size_t)(b0 + bb) * (NS * NL) + t * NL;
                float vp[NL], emt[NL];
#pragma unroll
                for (int i = 0; i < NL; i++) vp[i] = vpp[i];
#pragma unroll
                for (int j = 0; j < NL; j++) emt[j] = ge[j];
#pragma unroll
                for (int j = 0; j < NL; j++) {
                    float e = emt[j];
                    float val[NL];
#pragma unroll
                    for (int i = 0; i < NL; i++) val[i] = (vp[i] + s_T[i * NL + j]) + e;
                    bool c01 = val[0] >= val[1]; float m01 = c01 ? val[0] : val[1]; int i01 = c01 ? 0 : 1;
                    bool c23 = val[2] >= val[3]; float m23 = c23 ? val[2] : val[3]; int i23 = c23 ? 2 : 3;
                    bool c45 = val[4] >= val[5]; float m45 = c45 ? val[4] : val[5]; int i45 = c45 ? 4 : 5;
                    bool c67 = val[6] >= val[7]; float m67 = c67 ? val[6] : val[7]; int i67 = c67 ? 6 : 7;
                    bool ca = m01 >= m23; float ma = ca ? m01 : m23; int ia = ca ? i01 : i23;
                    bool cb = m45 >= m67; float mb = cb ? m45 : m67; int ib = cb ? i45 : i67;
                    bool cc = ma >= mb;  float mc = cc ? ma : mb;  int ic = cc ? ia : ib;
                    bool cd = mc >= val[8]; int bi = cd ? ic : 8;
                    s_bp[bb * BPST + t * NL + j] = (unsigned char)bi;
                }
            }
        }
        __syncthreads();
        // ---- phase 3: last tag + map-composition backtrack (wave w -> batch w) ----
        {
            int w = tid >> 6;
            const float* sv = s_v + w * VST;
            const unsigned char* bpp = s_bp + w * BPST;
            unsigned char* pth = s_path + w * NS;
            float bb2 = sv[(NS - 1) * NL + 0] + endT[0]; int lt = 0;
#pragma unroll
            for (int jj = 1; jj < NL; jj++) {
                float fj = sv[(NS - 1) * NL + jj] + endT[jj];
                if (fj > bb2) { bb2 = fj; lt = jj; }
            }
            unsigned long long G[8];
#pragma unroll
            for (int r = 0; r < 8; r++) {
                int t0 = (lane * 8 + r) * NL;
                unsigned long long g = 0;
                if (lane == 0 && r == 0) {
                    g = 0x876543210ULL;
                } else {
#pragma unroll
                    for (int x = 0; x < NL; x++) g |= (unsigned long long)bpp[t0 + x] << (4 * x);
                }
                G[r] = g;
            }
            unsigned long long A = 0x876543210ULL;
#pragma unroll
            for (int r = 7; r >= 0; r--) {
                unsigned long long An = 0;
#pragma unroll
                for (int x = 0; x < NL; x++) {
                    int ax = (int)((A >> (4 * x)) & 15ULL);
                    int gvv = (int)((G[r] >> (4 * ax)) & 15ULL);
                    An |= (unsigned long long)gvv << (4 * x);
                }
                A = An;
            }
            int e = 0; int cur = lt;
            for (int llv = 63; llv >= 0; --llv) {
                if (lane == llv) e = cur;
                unsigned long long Al = readlane_u64(A, llv);
                cur = (int)((Al >> (4 * cur)) & 15ULL);
            }
            unsigned long long pw = 0; int c2 = e;
#pragma unroll
            for (int r = 7; r >= 0; r--) {
                pw |= (unsigned long long)c2 << (8 * r);
                c2 = (int)((G[r] >> (4 * c2)) & 15ULL);
            }
            *(unsigned long long*)(pth + lane * 8) = pw;
        }
        __syncthreads();
        // ---- finalize: predict/label/correct for the block's 4 batches ----
        float cnt = 0.f;
#pragma unroll
        for (int q = 0; q < 8; q++) {
            int item = tid + q * 256;
            int bb = item >> 9;
            int t = item & (NS - 1);
            int b = b0 + bb;
            int idx = b * NS + t;
            int lab = label[idx];
            int p = (int)s_path[bb * NS + t];
            int pred = (lab > 0) ? p : 0;
            out[2 + idx] = (float)pred;
            out[2 + NROWS + idx] = (float)lab;
            cnt += (pred == lab) ? 1.f : 0.f;
        }
#pragma unroll
        for (int d = 1; d < 64; d <<= 1) cnt += __shfl_xor(cnt, d);
        if ((tid & 63) == 0) atomicAdd(out + 1, cnt);
    }
}

extern "C" void kernel_launch(void* const* d_in, const int* in_sizes, int n_in,
                              void* d_out, int out_size, void* d_ws, size_t ws_size,
                              hipStream_t stream) {
    const float* hidden = (const float*)d_in[0];
    const int*   label  = (const int*)d_in[1];
    const int*   mask   = (const int*)d_in[2];
    const float* W      = (const float*)d_in[3];
    const float* bias   = (const float*)d_in[4];
    const float* startT = (const float*)d_in[5];
    const float* endT   = (const float*)d_in[6];
    const float* trans  = (const float*)d_in[7];
    float* out = (float*)d_out;

    float* em = (float*)d_ws;   // EMN floats

    k_gemm<<<1024, 256, 0, stream>>>(hidden, W, bias, em, out);
    k_dp<<<32, 256, 0, stream>>>(em, label, mask, startT, endT, trans, out);
}